// Round 8
// baseline (122.875 us; speedup 1.0000x reference)
//
#include <hip/hip_runtime.h>
#include <hip/hip_fp16.h>
#include <math.h>

#define N_NODES 131072
#define E_EDGES 1048576
#define NDST    65536
#define NEG_SLOPE 0.2f
#define MAXDEG  64
#define NBUCK   1024       // buckets = dst>>6
#define DPB     64         // dsts per bucket
#define BCAP    1248       // bucket capacity (mean 1024 + 7 sigma)
#define BIN_BLOCKS 128     // bin blocks prepended to gemm grid

typedef __attribute__((ext_vector_type(8))) short short8;
typedef __attribute__((ext_vector_type(4))) float f32x4;

__device__ __forceinline__ unsigned short f2bf(float f) {
    unsigned u = __float_as_uint(f);
    u = (u + 0x7fffu + ((u >> 16) & 1u)) >> 16;
    return (unsigned short)u;
}
__device__ __forceinline__ __half2 u2h2(unsigned u) {
    union { unsigned u; __half2 h; } c; c.u = u; return c.h;
}
__device__ __forceinline__ unsigned h22u(__half2 h) {
    union { __half2 h; unsigned u; } c; c.h = h; return c.u;
}

// ---------------- K0: W [256][128] f32 -> Wt [128][256] bf16; also zero gcur
__global__ void prep_w(const float* __restrict__ W, unsigned short* __restrict__ Wt,
                       int* __restrict__ gcur) {
    int idx = blockIdx.x * 256 + threadIdx.x;   // 32768
    if (idx < NBUCK) gcur[idx] = 0;
    int k = idx >> 7, n = idx & 127;
    Wt[n * 256 + k] = f2bf(W[idx]);
}

// ---------------- K1: merged bin (blocks 0..127) + gemm (blocks 128..2175)
__global__ __launch_bounds__(512, 4) void gemm_bin(const float* __restrict__ A,
                                                   const unsigned short* __restrict__ Wt,
                                                   const float* __restrict__ attn_l,
                                                   const float* __restrict__ attn_r,
                                                   unsigned short* __restrict__ hout,
                                                   float* __restrict__ el,
                                                   float* __restrict__ er,
                                                   const int* __restrict__ src,
                                                   const int* __restrict__ dst,
                                                   int* __restrict__ gcur,
                                                   unsigned* __restrict__ ebuf) {
    __shared__ unsigned short lds[16384];   // gemm: swizzled A tile / repack scr; bin: 3x1024 ints
    const int t = threadIdx.x;

    if (blockIdx.x < BIN_BLOCKS) {
        // ---------------- bin path ----------------
        int* lh  = (int*)lds;
        int* lb  = lh + NBUCK;
        int* lh2 = lb + NBUCK;
        const int e0 = (blockIdx.x * 512 + t) * 16;
        int4 sv[4], dv[4];
#pragma unroll
        for (int i = 0; i < 4; ++i) {
            sv[i] = *(const int4*)(src + e0 + i * 4);
            dv[i] = *(const int4*)(dst + e0 + i * 4);
        }
        const int* s = (const int*)sv;
        const int* d = (const int*)dv;
        for (int i = t; i < NBUCK; i += 512) lh[i] = 0;
        __syncthreads();
#pragma unroll
        for (int k = 0; k < 16; ++k) atomicAdd(&lh[d[k] >> 6], 1);
        __syncthreads();
        for (int i = t; i < NBUCK; i += 512) {
            int c = lh[i];
            lb[i] = c ? atomicAdd(&gcur[i], c) : 0;
            lh2[i] = 0;
        }
        __syncthreads();
#pragma unroll
        for (int k = 0; k < 16; ++k) {
            int bk = d[k] >> 6;
            int r = lb[bk] + atomicAdd(&lh2[bk], 1);
            if (r < BCAP) ebuf[(size_t)bk * BCAP + r] = ((unsigned)s[k] << 6) | (unsigned)(d[k] & 63);
        }
        return;
    }

    // ---------------- gemm path ----------------
    const int w  = t >> 6, l = t & 63;
    const int n  = l & 15, kq = l >> 4;
    const int wm = w & 1,  wn = w >> 1;
    const size_t m0 = (size_t)(blockIdx.x - BIN_BLOCKS) * 64;

    short8 bfr[2][8];
    const unsigned short* wb = Wt + (size_t)(wn * 32 + n) * 256 + kq * 8;
#pragma unroll
    for (int nj = 0; nj < 2; ++nj)
#pragma unroll
        for (int s = 0; s < 8; ++s)
            bfr[nj][s] = *(const short8*)(wb + nj * 16 * 256 + s * 32);

    float4 tmp[8];
    const float4* gsrc = (const float4*)(A + m0 * 256);
#pragma unroll
    for (int i = 0; i < 8; ++i) tmp[i] = gsrc[i * 512 + t];
#pragma unroll
    for (int i = 0; i < 8; ++i) {
        int f   = i * 512 + t;
        int row = f >> 6, c4 = f & 63;
        unsigned lo = (unsigned)f2bf(tmp[i].x) | ((unsigned)f2bf(tmp[i].y) << 16);
        unsigned hi = (unsigned)f2bf(tmp[i].z) | ((unsigned)f2bf(tmp[i].w) << 16);
        unsigned byte = (unsigned)(row * 512) + (((unsigned)(c4 * 8)) ^ (((unsigned)(row & 7)) << 4));
        *(uint2*)((char*)lds + byte) = make_uint2(lo, hi);
    }
    __syncthreads();

    f32x4 acc[2][2];
#pragma unroll
    for (int mi = 0; mi < 2; ++mi)
#pragma unroll
        for (int nj = 0; nj < 2; ++nj) acc[mi][nj] = (f32x4){0.f, 0.f, 0.f, 0.f};

#pragma unroll
    for (int s = 0; s < 8; ++s) {
        short8 af[2];
#pragma unroll
        for (int mi = 0; mi < 2; ++mi) {
            int row = wm * 32 + mi * 16 + n;
            unsigned byte = (unsigned)(row * 512) +
                            (((unsigned)(s * 64 + kq * 16)) ^ (((unsigned)(row & 7)) << 4));
            af[mi] = *(const short8*)((char*)lds + byte);
        }
#pragma unroll
        for (int nj = 0; nj < 2; ++nj)
#pragma unroll
            for (int mi = 0; mi < 2; ++mi)
                acc[mi][nj] = __builtin_amdgcn_mfma_f32_16x16x32_bf16(af[mi], bfr[nj][s],
                                                                      acc[mi][nj], 0, 0, 0);
    }

    float al[2], ar[2];
#pragma unroll
    for (int nj = 0; nj < 2; ++nj) {
        al[nj] = attn_l[wn * 32 + nj * 16 + n];
        ar[nj] = attn_r[wn * 32 + nj * 16 + n];
    }
    float pl[2][4], pr[2][4];
#pragma unroll
    for (int mi = 0; mi < 2; ++mi)
#pragma unroll
        for (int i = 0; i < 4; ++i) {
            pl[mi][i] = acc[mi][0][i] * al[0] + acc[mi][1][i] * al[1];
            pr[mi][i] = acc[mi][0][i] * ar[0] + acc[mi][1][i] * ar[1];
        }
#pragma unroll
    for (int m = 1; m < 16; m <<= 1)
#pragma unroll
        for (int mi = 0; mi < 2; ++mi)
#pragma unroll
            for (int i = 0; i < 4; ++i) {
                pl[mi][i] += __shfl_xor(pl[mi][i], m);
                pr[mi][i] += __shfl_xor(pr[mi][i], m);
            }
    if (n == 0) {
#pragma unroll
        for (int mi = 0; mi < 2; ++mi)
#pragma unroll
            for (int i = 0; i < 4; ++i) {
                size_t row = m0 + wm * 32 + mi * 16 + kq * 4 + i;
                el[row * 4 + wn] = pl[mi][i];
                if (row < NDST) er[row * 4 + wn] = pr[mi][i];
            }
    }

    __syncthreads();
    unsigned short* scr = lds;              // [64][136] padded
#pragma unroll
    for (int mi = 0; mi < 2; ++mi)
#pragma unroll
        for (int nj = 0; nj < 2; ++nj)
#pragma unroll
            for (int i = 0; i < 4; ++i)
                scr[(wm * 32 + mi * 16 + kq * 4 + i) * 136 + wn * 32 + nj * 16 + n] =
                    __half_as_ushort(__float2half(acc[mi][nj][i]));
    __syncthreads();
#pragma unroll
    for (int j = 0; j < 2; ++j) {
        int c = j * 512 + t;
        int row = c >> 4, sub = c & 15;
        short8 v = *(const short8*)(scr + row * 136 + sub * 8);
        *(short8*)(hout + (m0 + row) * 128 + sub * 8) = v;
    }
}

// ---------------- K2: fused LDS-CSR build + per-dst softmax/aggregate
// one block per bucket: 512 thr, 8 waves x 8 dsts; rep-level el-prefetch pipeline
__global__ __launch_bounds__(512, 4) void agg_fused(const int* __restrict__ gcur,
                                                    const unsigned* __restrict__ ebuf,
                                                    const float* __restrict__ el,
                                                    const float* __restrict__ er,
                                                    const char* __restrict__ h,
                                                    float* __restrict__ out) {
    __shared__ int lcnt[DPB];
    __shared__ int lcsr[DPB * MAXDEG];
    __shared__ __align__(16) char stag[8 * 1536];
    const int t = threadIdx.x;
    const int w = t >> 6, lane = t & 63;
    const int b = blockIdx.x;
    if (b == 0 && t < 2) out[(size_t)NDST * 128 + t] = 1.0f;

    if (t < DPB) lcnt[t] = 0;
    __syncthreads();
    int nb = gcur[b]; if (nb > BCAP) nb = BCAP;
    for (int i = t; i < nb; i += 512) {
        unsigned e = ebuf[(size_t)b * BCAP + i];
        int dloc = e & 63;
        int pos = atomicAdd(&lcnt[dloc], 1);
        if (pos < MAXDEG) lcsr[dloc * MAXDEG + pos] = (int)(e >> 6);
    }
    __syncthreads();

    char* pbase = &stag[w * 1536];
    char* sbase = pbase + 1024;
    const int g = lane >> 4, q = lane & 15, head = q >> 2;
    const unsigned qoff = (unsigned)q * 16;
    const int dloc0 = w << 3;

    // ---- prologue of the rep pipeline: rep 0's inputs
    int degN = lcnt[dloc0]; if (degN > MAXDEG) degN = MAXDEG;
    bool vN = lane < degN;
    int sN = vN ? lcsr[dloc0 * MAXDEG + lane] : 0;
    float4 elN = *(const float4*)(el + (size_t)sN * 4);
    float4 erN = *(const float4*)(er + (size_t)(b * DPB + dloc0) * 4);

#pragma unroll 1
    for (int rep = 0; rep < 8; ++rep) {
        int dloc = dloc0 + rep;
        int wid = b * DPB + dloc;
        int deg = degN; bool valid = vN; int s = sN;
        float4 ev = elN; float4 er4 = erN;
        // issue next rep's gathers (hide el latency under this rep's work)
        if (rep < 7) {
            degN = lcnt[dloc + 1]; if (degN > MAXDEG) degN = MAXDEG;
            vN = lane < degN;
            sN = vN ? lcsr[(dloc + 1) * MAXDEG + lane] : 0;
            elN = *(const float4*)(el + (size_t)sN * 4);
            erN = *(const float4*)(er + (size_t)(wid + 1) * 4);
        }

        ev.x += er4.x; ev.y += er4.y; ev.z += er4.z; ev.w += er4.w;
        ev.x = ev.x > 0.f ? ev.x : NEG_SLOPE * ev.x;
        ev.y = ev.y > 0.f ? ev.y : NEG_SLOPE * ev.y;
        ev.z = ev.z > 0.f ? ev.z : NEG_SLOPE * ev.z;
        ev.w = ev.w > 0.f ? ev.w : NEG_SLOPE * ev.w;
        float4 p;
        p.x = valid ? __expf(ev.x) : 0.f;
        p.y = valid ? __expf(ev.y) : 0.f;
        p.z = valid ? __expf(ev.z) : 0.f;
        p.w = valid ? __expf(ev.w) : 0.f;

        float4 ss = p;
#pragma unroll
        for (int m = 1; m < 64; m <<= 1) {
            ss.x += __shfl_xor(ss.x, m);
            ss.y += __shfl_xor(ss.y, m);
            ss.z += __shfl_xor(ss.z, m);
            ss.w += __shfl_xor(ss.w, m);
        }

        if (valid) {
            uint4 pk;
            pk.x = h22u(__float2half2_rn(p.x));
            pk.y = h22u(__float2half2_rn(p.y));
            pk.z = h22u(__float2half2_rn(p.z));
            pk.w = h22u(__float2half2_rn(p.w));
            *(uint4*)(pbase + lane * 16) = pk;
            *(unsigned*)(sbase + lane * 4) = ((unsigned)s) << 8;   // s*128*2B
        }

        __half2 acc0 = u2h2(0), acc1 = u2h2(0), acc2 = u2h2(0), acc3 = u2h2(0);
        int it = (deg > g) ? ((deg - g + 3) >> 2) : 0;
        const char* pa = pbase + g * 16 + head * 4;
        const char* sa = sbase + g * 4;

        // 2-deep inner pipeline: two (pp,hv) sets in flight
        unsigned pp0 = 0, pp1 = 0;
        uint4 hv0 = make_uint4(0, 0, 0, 0), hv1 = make_uint4(0, 0, 0, 0);
        if (it > 0) {
            pp0 = *(const unsigned*)pa;
            hv0 = *(const uint4*)(h + *(const unsigned*)sa + qoff);
        }
        if (it > 1) {
            pp1 = *(const unsigned*)(pa + 64);
            hv1 = *(const uint4*)(h + *(const unsigned*)(sa + 16) + qoff);
        }
        int jj = 2;
#pragma unroll 1
        for (; jj + 1 < it; jj += 2) {
            unsigned npp0 = *(const unsigned*)(pa + (size_t)jj * 64);
            unsigned npp1 = *(const unsigned*)(pa + (size_t)jj * 64 + 64);
            unsigned ns0  = *(const unsigned*)(sa + (size_t)jj * 16);
            unsigned ns1  = *(const unsigned*)(sa + (size_t)jj * 16 + 16);
            uint4 nhv0 = *(const uint4*)(h + ns0 + qoff);
            uint4 nhv1 = *(const uint4*)(h + ns1 + qoff);
            __half2 pA = u2h2(pp0), pB = u2h2(pp1);
            acc0 = __hfma2(u2h2(hv0.x), pA, acc0);
            acc1 = __hfma2(u2h2(hv0.y), pA, acc1);
            acc2 = __hfma2(u2h2(hv0.z), pA, acc2);
            acc3 = __hfma2(u2h2(hv0.w), pA, acc3);
            acc0 = __hfma2(u2h2(hv1.x), pB, acc0);
            acc1 = __hfma2(u2h2(hv1.y), pB, acc1);
            acc2 = __hfma2(u2h2(hv1.z), pB, acc2);
            acc3 = __hfma2(u2h2(hv1.w), pB, acc3);
            pp0 = npp0; hv0 = nhv0; pp1 = npp1; hv1 = nhv1;
        }
        if (jj < it) {
            unsigned npp0 = *(const unsigned*)(pa + (size_t)jj * 64);
            unsigned ns0  = *(const unsigned*)(sa + (size_t)jj * 16);
            uint4 nhv0 = *(const uint4*)(h + ns0 + qoff);
            __half2 pA = u2h2(pp0);
            acc0 = __hfma2(u2h2(hv0.x), pA, acc0);
            acc1 = __hfma2(u2h2(hv0.y), pA, acc1);
            acc2 = __hfma2(u2h2(hv0.z), pA, acc2);
            acc3 = __hfma2(u2h2(hv0.w), pA, acc3);
            pp0 = npp0; hv0 = nhv0;
        }
        {
            __half2 pA = u2h2(pp0), pB = u2h2(pp1);
            acc0 = __hfma2(u2h2(hv0.x), pA, acc0);
            acc1 = __hfma2(u2h2(hv0.y), pA, acc1);
            acc2 = __hfma2(u2h2(hv0.z), pA, acc2);
            acc3 = __hfma2(u2h2(hv0.w), pA, acc3);
            acc0 = __hfma2(u2h2(hv1.x), pB, acc0);
            acc1 = __hfma2(u2h2(hv1.y), pB, acc1);
            acc2 = __hfma2(u2h2(hv1.z), pB, acc2);
            acc3 = __hfma2(u2h2(hv1.w), pB, acc3);
        }

        float2 f0 = __half22float2(acc0);
        float2 f1 = __half22float2(acc1);
        float2 f2 = __half22float2(acc2);
        float2 f3 = __half22float2(acc3);
        float fa[8] = {f0.x, f0.y, f1.x, f1.y, f2.x, f2.y, f3.x, f3.y};
#pragma unroll
        for (int m = 16; m < 64; m <<= 1)
#pragma unroll
            for (int k = 0; k < 8; ++k) fa[k] += __shfl_xor(fa[k], m);

        if (g == 0) {
            float slo  = (head & 1) ? ss.y : ss.x;
            float shi  = (head & 1) ? ss.w : ss.z;
            float ssel = (head & 2) ? shi : slo;
            float inv  = ssel > 0.f ? 1.0f / ssel : 0.f;
            float o[8];
#pragma unroll
            for (int k = 0; k < 8; ++k) {
                float v = fa[k] * inv;
                o[k] = v > 0.f ? v : expm1f(v);
            }
            float* op = out + (size_t)wid * 128 + q * 8;
            *(float4*)(op)     = make_float4(o[0], o[1], o[2], o[3]);
            *(float4*)(op + 4) = make_float4(o[4], o[5], o[6], o[7]);
        }
    }
}

extern "C" void kernel_launch(void* const* d_in, const int* in_sizes, int n_in,
                              void* d_out, int out_size, void* d_ws, size_t ws_size,
                              hipStream_t stream) {
    const float* feats  = (const float*)d_in[0];
    const int*   src    = (const int*)d_in[1];
    const int*   dst    = (const int*)d_in[2];
    const float* W      = (const float*)d_in[3];
    const float* attn_l = (const float*)d_in[4];
    const float* attn_r = (const float*)d_in[5];
    float* out = (float*)d_out;

    char* base = (char*)d_ws;
    unsigned short* h_16 = (unsigned short*)base;                 // 33,554,432 B (fp16)
    size_t off = (size_t)N_NODES * 128 * 2;
    unsigned short* Wt = (unsigned short*)(base + off); off += 65536;
    float* el  = (float*)(base + off); off += (size_t)N_NODES * 4 * 4;
    float* er  = (float*)(base + off); off += (size_t)NDST * 4 * 4;
    int*   gcur = (int*)(base + off);  off += (size_t)NBUCK * 4;
    unsigned* ebuf = (unsigned*)(base + off);   // 1024*1248*4 ~= 5.1 MB

    prep_w<<<128, 256, 0, stream>>>(W, Wt, gcur);
    gemm_bin<<<BIN_BLOCKS + N_NODES / 64, 512, 0, stream>>>(feats, Wt, attn_l, attn_r,
                                                            h_16, el, er, src, dst, gcur, ebuf);
    agg_fused<<<NBUCK, 512, 0, stream>>>(gcur, ebuf, el, er, (const char*)h_16, out);
}

// Round 9
// 115.621 us; speedup vs baseline: 1.0627x; 1.0627x over previous
//
#include <hip/hip_runtime.h>
#include <hip/hip_fp16.h>
#include <math.h>

#define N_NODES 131072
#define E_EDGES 1048576
#define NDST    65536
#define NEG_SLOPE 0.2f
#define MAXDEG  64
#define NBUCK   1024       // buckets = dst>>6
#define DPB     64         // dsts per bucket
#define BCAP    1248       // bucket capacity (mean 1024 + 7 sigma)
#define BIN_BLOCKS 128     // bin blocks prepended to gemm grid

typedef __attribute__((ext_vector_type(8))) short short8;
typedef __attribute__((ext_vector_type(4))) float f32x4;

__device__ __forceinline__ unsigned short f2bf(float f) {
    unsigned u = __float_as_uint(f);
    u = (u + 0x7fffu + ((u >> 16) & 1u)) >> 16;
    return (unsigned short)u;
}
__device__ __forceinline__ __half2 u2h2(unsigned u) {
    union { unsigned u; __half2 h; } c; c.u = u; return c.h;
}
__device__ __forceinline__ unsigned h22u(__half2 h) {
    union { __half2 h; unsigned u; } c; c.h = h; return c.u;
}

// ---------------- K0: W [256][128] f32 -> Wt [128][256] bf16; also zero gcur
__global__ void prep_w(const float* __restrict__ W, unsigned short* __restrict__ Wt,
                       int* __restrict__ gcur) {
    int idx = blockIdx.x * 256 + threadIdx.x;   // 32768
    if (idx < NBUCK) gcur[idx] = 0;
    int k = idx >> 7, n = idx & 127;
    Wt[n * 256 + k] = f2bf(W[idx]);
}

// ---------------- K1: merged bin (blocks 0..127) + gemm (blocks 128..2175)
__global__ __launch_bounds__(512, 4) void gemm_bin(const float* __restrict__ A,
                                                   const unsigned short* __restrict__ Wt,
                                                   const float* __restrict__ attn_l,
                                                   const float* __restrict__ attn_r,
                                                   unsigned short* __restrict__ hout,
                                                   float* __restrict__ el,
                                                   float* __restrict__ er,
                                                   const int* __restrict__ src,
                                                   const int* __restrict__ dst,
                                                   int* __restrict__ gcur,
                                                   unsigned* __restrict__ ebuf) {
    __shared__ unsigned short lds[16384];   // gemm: swizzled A tile / repack scr; bin: 3x1024 ints
    const int t = threadIdx.x;

    if (blockIdx.x < BIN_BLOCKS) {
        // ---------------- bin path ----------------
        int* lh  = (int*)lds;
        int* lb  = lh + NBUCK;
        int* lh2 = lb + NBUCK;
        const int e0 = (blockIdx.x * 512 + t) * 16;
        int4 sv[4], dv[4];
#pragma unroll
        for (int i = 0; i < 4; ++i) {
            sv[i] = *(const int4*)(src + e0 + i * 4);
            dv[i] = *(const int4*)(dst + e0 + i * 4);
        }
        const int* s = (const int*)sv;
        const int* d = (const int*)dv;
        for (int i = t; i < NBUCK; i += 512) lh[i] = 0;
        __syncthreads();
#pragma unroll
        for (int k = 0; k < 16; ++k) atomicAdd(&lh[d[k] >> 6], 1);
        __syncthreads();
        for (int i = t; i < NBUCK; i += 512) {
            int c = lh[i];
            lb[i] = c ? atomicAdd(&gcur[i], c) : 0;
            lh2[i] = 0;
        }
        __syncthreads();
#pragma unroll
        for (int k = 0; k < 16; ++k) {
            int bk = d[k] >> 6;
            int r = lb[bk] + atomicAdd(&lh2[bk], 1);
            if (r < BCAP) ebuf[(size_t)bk * BCAP + r] = ((unsigned)s[k] << 6) | (unsigned)(d[k] & 63);
        }
        return;
    }

    // ---------------- gemm path ----------------
    const int w  = t >> 6, l = t & 63;
    const int n  = l & 15, kq = l >> 4;
    const int wm = w & 1,  wn = w >> 1;
    const size_t m0 = (size_t)(blockIdx.x - BIN_BLOCKS) * 64;

    short8 bfr[2][8];
    const unsigned short* wb = Wt + (size_t)(wn * 32 + n) * 256 + kq * 8;
#pragma unroll
    for (int nj = 0; nj < 2; ++nj)
#pragma unroll
        for (int s = 0; s < 8; ++s)
            bfr[nj][s] = *(const short8*)(wb + nj * 16 * 256 + s * 32);

    float4 tmp[8];
    const float4* gsrc = (const float4*)(A + m0 * 256);
#pragma unroll
    for (int i = 0; i < 8; ++i) tmp[i] = gsrc[i * 512 + t];
#pragma unroll
    for (int i = 0; i < 8; ++i) {
        int f   = i * 512 + t;
        int row = f >> 6, c4 = f & 63;
        unsigned lo = (unsigned)f2bf(tmp[i].x) | ((unsigned)f2bf(tmp[i].y) << 16);
        unsigned hi = (unsigned)f2bf(tmp[i].z) | ((unsigned)f2bf(tmp[i].w) << 16);
        unsigned byte = (unsigned)(row * 512) + (((unsigned)(c4 * 8)) ^ (((unsigned)(row & 7)) << 4));
        *(uint2*)((char*)lds + byte) = make_uint2(lo, hi);
    }
    __syncthreads();

    f32x4 acc[2][2];
#pragma unroll
    for (int mi = 0; mi < 2; ++mi)
#pragma unroll
        for (int nj = 0; nj < 2; ++nj) acc[mi][nj] = (f32x4){0.f, 0.f, 0.f, 0.f};

#pragma unroll
    for (int s = 0; s < 8; ++s) {
        short8 af[2];
#pragma unroll
        for (int mi = 0; mi < 2; ++mi) {
            int row = wm * 32 + mi * 16 + n;
            unsigned byte = (unsigned)(row * 512) +
                            (((unsigned)(s * 64 + kq * 16)) ^ (((unsigned)(row & 7)) << 4));
            af[mi] = *(const short8*)((char*)lds + byte);
        }
#pragma unroll
        for (int nj = 0; nj < 2; ++nj)
#pragma unroll
            for (int mi = 0; mi < 2; ++mi)
                acc[mi][nj] = __builtin_amdgcn_mfma_f32_16x16x32_bf16(af[mi], bfr[nj][s],
                                                                      acc[mi][nj], 0, 0, 0);
    }

    float al[2], ar[2];
#pragma unroll
    for (int nj = 0; nj < 2; ++nj) {
        al[nj] = attn_l[wn * 32 + nj * 16 + n];
        ar[nj] = attn_r[wn * 32 + nj * 16 + n];
    }
    float pl[2][4], pr[2][4];
#pragma unroll
    for (int mi = 0; mi < 2; ++mi)
#pragma unroll
        for (int i = 0; i < 4; ++i) {
            pl[mi][i] = acc[mi][0][i] * al[0] + acc[mi][1][i] * al[1];
            pr[mi][i] = acc[mi][0][i] * ar[0] + acc[mi][1][i] * ar[1];
        }
#pragma unroll
    for (int m = 1; m < 16; m <<= 1)
#pragma unroll
        for (int mi = 0; mi < 2; ++mi)
#pragma unroll
            for (int i = 0; i < 4; ++i) {
                pl[mi][i] += __shfl_xor(pl[mi][i], m);
                pr[mi][i] += __shfl_xor(pr[mi][i], m);
            }
    if (n == 0) {
#pragma unroll
        for (int mi = 0; mi < 2; ++mi)
#pragma unroll
            for (int i = 0; i < 4; ++i) {
                size_t row = m0 + wm * 32 + mi * 16 + kq * 4 + i;
                el[row * 4 + wn] = pl[mi][i];
                if (row < NDST) er[row * 4 + wn] = pr[mi][i];
            }
    }

    __syncthreads();
    unsigned short* scr = lds;              // [64][136] padded
#pragma unroll
    for (int mi = 0; mi < 2; ++mi)
#pragma unroll
        for (int nj = 0; nj < 2; ++nj)
#pragma unroll
            for (int i = 0; i < 4; ++i)
                scr[(wm * 32 + mi * 16 + kq * 4 + i) * 136 + wn * 32 + nj * 16 + n] =
                    __half_as_ushort(__float2half(acc[mi][nj][i]));
    __syncthreads();
#pragma unroll
    for (int j = 0; j < 2; ++j) {
        int c = j * 512 + t;
        int row = c >> 4, sub = c & 15;
        short8 v = *(const short8*)(scr + row * 136 + sub * 8);
        *(short8*)(hout + (m0 + row) * 128 + sub * 8) = v;
    }
}

// ---------------- K2: fused LDS-CSR build + per-dst softmax/aggregate
// one block per bucket: 512 thr, 8 waves x 8 dsts; 2-deep inner gather pipeline
__global__ __launch_bounds__(512, 4) void agg_fused(const int* __restrict__ gcur,
                                                    const unsigned* __restrict__ ebuf,
                                                    const float* __restrict__ el,
                                                    const float* __restrict__ er,
                                                    const char* __restrict__ h,
                                                    float* __restrict__ out) {
    __shared__ int lcnt[DPB];
    __shared__ int lcsr[DPB * MAXDEG];
    __shared__ __align__(16) char stag[8 * 1536];
    const int t = threadIdx.x;
    const int w = t >> 6, lane = t & 63;
    const int b = blockIdx.x;
    if (b == 0 && t < 2) out[(size_t)NDST * 128 + t] = 1.0f;

    if (t < DPB) lcnt[t] = 0;
    __syncthreads();
    int nb = gcur[b]; if (nb > BCAP) nb = BCAP;
    for (int i = t; i < nb; i += 512) {
        unsigned e = ebuf[(size_t)b * BCAP + i];
        int dloc = e & 63;
        int pos = atomicAdd(&lcnt[dloc], 1);
        if (pos < MAXDEG) lcsr[dloc * MAXDEG + pos] = (int)(e >> 6);
    }
    __syncthreads();

    char* pbase = &stag[w * 1536];
    char* sbase = pbase + 1024;
    const int g = lane >> 4, q = lane & 15, head = q >> 2;
    const unsigned qoff = (unsigned)q * 16;

#pragma unroll 1
    for (int rep = 0; rep < 8; ++rep) {
        int dloc = (w << 3) + rep;
        int wid = b * DPB + dloc;
        int deg = lcnt[dloc]; if (deg > MAXDEG) deg = MAXDEG;
        float4 er4 = *(const float4*)(er + (size_t)wid * 4);

        bool valid = lane < deg;
        int s = valid ? lcsr[dloc * MAXDEG + lane] : 0;
        float4 ev = *(const float4*)(el + (size_t)s * 4);
        ev.x += er4.x; ev.y += er4.y; ev.z += er4.z; ev.w += er4.w;
        ev.x = ev.x > 0.f ? ev.x : NEG_SLOPE * ev.x;
        ev.y = ev.y > 0.f ? ev.y : NEG_SLOPE * ev.y;
        ev.z = ev.z > 0.f ? ev.z : NEG_SLOPE * ev.z;
        ev.w = ev.w > 0.f ? ev.w : NEG_SLOPE * ev.w;
        float4 p;
        p.x = valid ? __expf(ev.x) : 0.f;
        p.y = valid ? __expf(ev.y) : 0.f;
        p.z = valid ? __expf(ev.z) : 0.f;
        p.w = valid ? __expf(ev.w) : 0.f;

        float4 ss = p;
#pragma unroll
        for (int m = 1; m < 64; m <<= 1) {
            ss.x += __shfl_xor(ss.x, m);
            ss.y += __shfl_xor(ss.y, m);
            ss.z += __shfl_xor(ss.z, m);
            ss.w += __shfl_xor(ss.w, m);
        }

        if (valid) {
            uint4 pk;
            pk.x = h22u(__float2half2_rn(p.x));
            pk.y = h22u(__float2half2_rn(p.y));
            pk.z = h22u(__float2half2_rn(p.z));
            pk.w = h22u(__float2half2_rn(p.w));
            *(uint4*)(pbase + lane * 16) = pk;
            *(unsigned*)(sbase + lane * 4) = ((unsigned)s) << 8;   // s*128*2B
        }

        __half2 acc0 = u2h2(0), acc1 = u2h2(0), acc2 = u2h2(0), acc3 = u2h2(0);
        int it = (deg > g) ? ((deg - g + 3) >> 2) : 0;
        const char* pa = pbase + g * 16 + head * 4;
        const char* sa = sbase + g * 4;

        // 2-slot shift-register pipeline: 2 h-loads in flight during FMA
        unsigned pp0 = 0, pp1 = 0;
        uint4 hv0 = make_uint4(0, 0, 0, 0), hv1 = make_uint4(0, 0, 0, 0);
        if (it > 0) {
            pp0 = *(const unsigned*)pa;
            hv0 = *(const uint4*)(h + *(const unsigned*)sa + qoff);
        }
        if (it > 1) {
            pp1 = *(const unsigned*)(pa + 64);
            hv1 = *(const uint4*)(h + *(const unsigned*)(sa + 16) + qoff);
        }
#pragma unroll 1
        for (int j = 2; j < it; ++j) {
            unsigned npp = *(const unsigned*)(pa + (size_t)j * 64);
            unsigned ns  = *(const unsigned*)(sa + (size_t)j * 16);
            uint4 nhv = *(const uint4*)(h + ns + qoff);
            __half2 pA = u2h2(pp0);
            acc0 = __hfma2(u2h2(hv0.x), pA, acc0);
            acc1 = __hfma2(u2h2(hv0.y), pA, acc1);
            acc2 = __hfma2(u2h2(hv0.z), pA, acc2);
            acc3 = __hfma2(u2h2(hv0.w), pA, acc3);
            pp0 = pp1; hv0 = hv1;
            pp1 = npp; hv1 = nhv;
        }
        {
            __half2 pA = u2h2(pp0), pB = u2h2(pp1);
            acc0 = __hfma2(u2h2(hv0.x), pA, acc0);
            acc1 = __hfma2(u2h2(hv0.y), pA, acc1);
            acc2 = __hfma2(u2h2(hv0.z), pA, acc2);
            acc3 = __hfma2(u2h2(hv0.w), pA, acc3);
            acc0 = __hfma2(u2h2(hv1.x), pB, acc0);
            acc1 = __hfma2(u2h2(hv1.y), pB, acc1);
            acc2 = __hfma2(u2h2(hv1.z), pB, acc2);
            acc3 = __hfma2(u2h2(hv1.w), pB, acc3);
        }

        float2 f0 = __half22float2(acc0);
        float2 f1 = __half22float2(acc1);
        float2 f2 = __half22float2(acc2);
        float2 f3 = __half22float2(acc3);
        float fa[8] = {f0.x, f0.y, f1.x, f1.y, f2.x, f2.y, f3.x, f3.y};
#pragma unroll
        for (int m = 16; m < 64; m <<= 1)
#pragma unroll
            for (int k = 0; k < 8; ++k) fa[k] += __shfl_xor(fa[k], m);

        if (g == 0) {
            float slo  = (head & 1) ? ss.y : ss.x;
            float shi  = (head & 1) ? ss.w : ss.z;
            float ssel = (head & 2) ? shi : slo;
            float inv  = ssel > 0.f ? 1.0f / ssel : 0.f;
            float o[8];
#pragma unroll
            for (int k = 0; k < 8; ++k) {
                float v = fa[k] * inv;
                o[k] = v > 0.f ? v : expm1f(v);
            }
            float* op = out + (size_t)wid * 128 + q * 8;
            *(float4*)(op)     = make_float4(o[0], o[1], o[2], o[3]);
            *(float4*)(op + 4) = make_float4(o[4], o[5], o[6], o[7]);
        }
    }
}

extern "C" void kernel_launch(void* const* d_in, const int* in_sizes, int n_in,
                              void* d_out, int out_size, void* d_ws, size_t ws_size,
                              hipStream_t stream) {
    const float* feats  = (const float*)d_in[0];
    const int*   src    = (const int*)d_in[1];
    const int*   dst    = (const int*)d_in[2];
    const float* W      = (const float*)d_in[3];
    const float* attn_l = (const float*)d_in[4];
    const float* attn_r = (const float*)d_in[5];
    float* out = (float*)d_out;

    char* base = (char*)d_ws;
    unsigned short* h_16 = (unsigned short*)base;                 // 33,554,432 B (fp16)
    size_t off = (size_t)N_NODES * 128 * 2;
    unsigned short* Wt = (unsigned short*)(base + off); off += 65536;
    float* el  = (float*)(base + off); off += (size_t)N_NODES * 4 * 4;
    float* er  = (float*)(base + off); off += (size_t)NDST * 4 * 4;
    int*   gcur = (int*)(base + off);  off += (size_t)NBUCK * 4;
    unsigned* ebuf = (unsigned*)(base + off);   // 1024*1248*4 ~= 5.1 MB

    prep_w<<<128, 256, 0, stream>>>(W, Wt, gcur);
    gemm_bin<<<BIN_BLOCKS + N_NODES / 64, 512, 0, stream>>>(feats, Wt, attn_l, attn_r,
                                                            h_16, el, er, src, dst, gcur, ebuf);
    agg_fused<<<NBUCK, 512, 0, stream>>>(gcur, ebuf, el, er, (const char*)h_16, out);
}